// Round 4
// baseline (82.524 us; speedup 1.0000x reference)
//
#include <hip/hip_runtime.h>
#include <math.h>

// Problem constants
#define BB 128
#define ND 32
#define NIJ 16384
#define EPS2 0.25f
#define EPS4 0.0625f

// Tiling: 512 blocks = 256 ij-chunks x 2 b-halves; 64 ij + 64 b per block.
// 512 thr: lane map gij[0-2] nq[3-4] bl[5-8].
// Each thread: 4 b (bl+16*rb, within half) x 8 ij (gij+8*it) x 8 n (nq*8).
// 2 blocks/CU resident (43.5 KB LDS, 128-VGPR cap) -> barrier/tail overlap.
#define TIJ 64
#define NBLK 512
#define NTHR 512
#define ROWF 132                // coef row: cA32|cB32|K32|KV32|pad4

// LDS layout (floats)
#define XS_OFF  8448            // X stage [64][36] (this half's rows)
#define CC_OFF  10752
#define LAM_OFF 10816
#define LDS_FL  10880           // 43.5 KB
#define STG_ROW 36

// part layout per slice (packed): num[64][32] @0, den[64] @2048
#define PART_STRIDE 2112
#define DEN_OFF_P 2048

__global__ __launch_bounds__(NTHR, 4) void gmm_fused(
    const float* __restrict__ Xg,
    const float* __restrict__ tptr,
    const float* __restrict__ Mu0, const float* __restrict__ Mu1,
    const float* __restrict__ S0,  const float* __restrict__ S1,
    const float* __restrict__ Lam,
    float* __restrict__ part)
{
    __shared__ __align__(16) float lds[LDS_FL];

    const int tid  = threadIdx.x;
    const int blk  = blockIdx.x;
    const int ijc  = blk >> 1;          // ij-chunk 0..255
    const int half = blk & 1;           // b-half
    const int ij0g = ijc * TIJ;
    const int b0   = half * 64;
    const float t   = tptr[0];
    const float omt = 1.0f - t;

    // ---- Phase 1a: this half's X rows -> LDS [64][36], 1 float4/thread ----
    {
        const int idx = tid * 4;           // 2048 floats
        *(float4*)&lds[XS_OFF + (idx >> 5) * STG_ROW + (idx & 31)] =
            *(const float4*)&Xg[b0 * ND + idx];
    }

    // ---- Phase 1b: per-(ij, n) coefficients into LDS ----
    // 64 ij * 32 n = 2048 pairs over 512 threads -> 4 each
#pragma unroll
    for (int k = 0; k < (TIJ * ND) / NTHR; ++k) {
        const int idx = tid + k * NTHR;
        const int ijl = idx >> 5;          // 0..63
        const int n   = idx & 31;
        const int ij  = ij0g + ijl;
        const int i   = ij >> 7;
        const int j   = ij & 127;
        const float s0  = S0[i * ND + n];
        const float s1  = S1[j * ND + n];
        const float mu0 = Mu0[i * ND + n];
        const float mu1 = Mu1[j * ND + n];
        const float Ds  = sqrtf(4.0f * s0 * s1 + EPS4);
        const float Cs  = 0.5f * (Ds - EPS2);
        const float Sigma = omt * omt * s0 + t * t * s1
                          + 2.0f * t * omt * Cs + EPS2 * t * omt;
        const float St  = (t * s1 + omt * Cs) - (omt * s0 + t * Cs) - EPS2 * t;
        const float Mut = omt * mu0 + t * mu1;
        const float v   = mu1 - mu0;
        const float invS = 1.0f / Sigma;
        const float Kf  = St * invS;
        const float cA  = -0.5f * invS;
        const float cB  = Mut * invS;
        lds[ijl * ROWF + n]      = cA;
        lds[ijl * ROWF + 32 + n] = cB;
        lds[ijl * ROWF + 64 + n] = Kf;
        lds[ijl * ROWF + 96 + n] = v - Kf * Mut;
        float cc = cA * Mut * Mut - 0.5f * __logf(Sigma);
        cc += __shfl_xor(cc, 1);
        cc += __shfl_xor(cc, 2);
        cc += __shfl_xor(cc, 4);
        cc += __shfl_xor(cc, 8);
        cc += __shfl_xor(cc, 16);
        if (n == 0) lds[CC_OFF + ijl] = cc;
    }
    if (tid < TIJ) lds[LAM_OFF + tid] = Lam[ij0g + tid];

    __syncthreads();

    // ---- Thread mapping: 4 b x 8 ij x 8 n (within this b-half) ----
    const int gij = tid & 7;          // lane bits 0-2: ij within group
    const int nq  = (tid >> 3) & 3;   // lane bits 3-4: n-quarter
    const int bl  = tid >> 5;         // 0..15 -> local b in {bl+16*rb}
    const int n0  = nq * 8;

    // X quarter-rows -> registers
    float x[4][8];
#pragma unroll
    for (int rb = 0; rb < 4; ++rb) {
        const float4 v4 = *(const float4*)&lds[XS_OFF + (bl + 16 * rb) * STG_ROW + n0];
        const float4 w4 = *(const float4*)&lds[XS_OFF + (bl + 16 * rb) * STG_ROW + n0 + 4];
        x[rb][0] = v4.x; x[rb][1] = v4.y; x[rb][2] = v4.z; x[rb][3] = v4.w;
        x[rb][4] = w4.x; x[rb][5] = w4.y; x[rb][6] = w4.z; x[rb][7] = w4.w;
    }

    float num[4][8];
#pragma unroll
    for (int rb = 0; rb < 4; ++rb)
#pragma unroll
        for (int n = 0; n < 8; ++n) num[rb][n] = 0.0f;
    float den[4] = {0.0f, 0.0f, 0.0f, 0.0f};

    // ---- Phase 2: 8 iters; coef quarter-row shared by 4 b ----
#pragma unroll
    for (int it = 0; it < TIJ / 8; ++it) {
        const int ijl = gij + (it << 3);
        const float* __restrict__ row = &lds[ijl * ROWF + n0];
        const float4 a0 = *(const float4*)&row[0];
        const float4 a1 = *(const float4*)&row[4];
        const float4 b0q = *(const float4*)&row[32];
        const float4 b1q = *(const float4*)&row[36];

        float la[4], lb[4];
#pragma unroll
        for (int rb = 0; rb < 4; ++rb) {
            float u = fmaf(fmaf(a0.x, x[rb][0], b0q.x), x[rb][0], 0.0f);
            float v = fmaf(fmaf(a0.y, x[rb][1], b0q.y), x[rb][1], 0.0f);
            u = fmaf(fmaf(a0.z, x[rb][2], b0q.z), x[rb][2], u);
            v = fmaf(fmaf(a0.w, x[rb][3], b0q.w), x[rb][3], v);
            u = fmaf(fmaf(a1.x, x[rb][4], b1q.x), x[rb][4], u);
            v = fmaf(fmaf(a1.y, x[rb][5], b1q.y), x[rb][5], v);
            u = fmaf(fmaf(a1.z, x[rb][6], b1q.z), x[rb][6], u);
            v = fmaf(fmaf(a1.w, x[rb][7], b1q.w), x[rb][7], v);
            la[rb] = u; lb[rb] = v;
        }

        // issue num-coef loads early; latency hidden under fold+exp
        const float4 k0 = *(const float4*)&row[64];
        const float4 k1 = *(const float4*)&row[68];
        const float4 v0 = *(const float4*)&row[96];
        const float4 v1 = *(const float4*)&row[100];
        const float cc0 = lds[CC_OFF + ijl];
        const float lam = lds[LAM_OFF + ijl];

        float w[4];
#pragma unroll
        for (int rb = 0; rb < 4; ++rb) {
            float lw = la[rb] + lb[rb];
            lw += __shfl_xor(lw, 8);       // fold nq bit 0
            lw += __shfl_xor(lw, 16);      // fold nq bit 1
            lw = fminf(fmaxf(lw + cc0, -50.0f), 50.0f);
            w[rb] = __expf(lw) * lam;
            den[rb] += w[rb];
        }

#pragma unroll
        for (int rb = 0; rb < 4; ++rb) {
            num[rb][0] = fmaf(w[rb], fmaf(k0.x, x[rb][0], v0.x), num[rb][0]);
            num[rb][1] = fmaf(w[rb], fmaf(k0.y, x[rb][1], v0.y), num[rb][1]);
            num[rb][2] = fmaf(w[rb], fmaf(k0.z, x[rb][2], v0.z), num[rb][2]);
            num[rb][3] = fmaf(w[rb], fmaf(k0.w, x[rb][3], v0.w), num[rb][3]);
            num[rb][4] = fmaf(w[rb], fmaf(k1.x, x[rb][4], v1.x), num[rb][4]);
            num[rb][5] = fmaf(w[rb], fmaf(k1.y, x[rb][5], v1.y), num[rb][5]);
            num[rb][6] = fmaf(w[rb], fmaf(k1.z, x[rb][6], v1.z), num[rb][6]);
            num[rb][7] = fmaf(w[rb], fmaf(k1.w, x[rb][7], v1.w), num[rb][7]);
        }
    }

    // ---- Fold-reduce across the 8 gij lanes: 8 cols -> 1 col/lane ----
#pragma unroll
    for (int rb = 0; rb < 4; ++rb) {
#pragma unroll
        for (int c = 0; c < 4; ++c) {      // mask 4: 8 -> 4
            const float s = (gij & 4) ? num[rb][c] : num[rb][c + 4];
            const float r = __shfl_xor(s, 4);
            num[rb][c] = ((gij & 4) ? num[rb][c + 4] : num[rb][c]) + r;
        }
#pragma unroll
        for (int c = 0; c < 2; ++c) {      // mask 2: 4 -> 2
            const float s = (gij & 2) ? num[rb][c] : num[rb][c + 2];
            const float r = __shfl_xor(s, 2);
            num[rb][c] = ((gij & 2) ? num[rb][c + 2] : num[rb][c]) + r;
        }
        {                                   // mask 1: 2 -> 1
            const float s = (gij & 1) ? num[rb][0] : num[rb][1];
            const float r = __shfl_xor(s, 1);
            num[rb][0] = ((gij & 1) ? num[rb][1] : num[rb][0]) + r;
        }
        den[rb] += __shfl_xor(den[rb], 1);
        den[rb] += __shfl_xor(den[rb], 2);
        den[rb] += __shfl_xor(den[rb], 4);
    }

    // ---- Direct coalesced global store ----
    // Lane (gij, nq) holds col nq*8+gij = tid&31; wave = 2 bl x 32 cols
    // -> 256 B contiguous per scalar store inst.
    float* __restrict__ dstg = part + (size_t)blk * PART_STRIDE;
    const int col = (tid & 31);
#pragma unroll
    for (int rb = 0; rb < 4; ++rb) {
        dstg[(bl + 16 * rb) * 32 + col] = num[rb][0];
    }
    if (col == 0) {
#pragma unroll
        for (int rb = 0; rb < 4; ++rb) {
            dstg[DEN_OFF_P + bl + 16 * rb] = den[rb];
        }
    }
}

// 128 blocks (one per b), 256 thr = 32 sg x 8 c4. float4 loads:
// per wave-inst 8 slices x 128 B contiguous = 1 KB.
__global__ __launch_bounds__(256) void gmm_reduce(
    const float* __restrict__ part,
    float* __restrict__ out)
{
    const int b    = blockIdx.x;           // 0..127
    const int half = b >> 6;
    const int lb   = b & 63;
    const int tid  = threadIdx.x;
    const int c4   = tid & 7;              // float4 column group
    const int sg   = tid >> 3;             // 0..31 slice-groups

    float4 acc = make_float4(0.0f, 0.0f, 0.0f, 0.0f);
    float accd = 0.0f;
#pragma unroll
    for (int g = 0; g < 8; ++g) {
        const int ijc = sg + g * 32;       // 0..255
        const size_t base = (size_t)(ijc * 2 + half) * PART_STRIDE;
        const float4 v = *(const float4*)&part[base + lb * 32 + c4 * 4];
        acc.x += v.x; acc.y += v.y; acc.z += v.z; acc.w += v.w;
        accd += part[base + DEN_OFF_P + lb];   // broadcast across c4 lanes
    }

    __shared__ float red[32][36];
    *(float4*)&red[sg][c4 * 4] = acc;
    if (c4 == 0) red[sg][32] = accd;
    __syncthreads();

    if (tid < 32) {
        float ns = 0.0f, ds = 0.0f;
#pragma unroll
        for (int k = 0; k < 32; ++k) {
            ns += red[k][tid];
            ds += red[k][32];
        }
        out[b * 32 + tid] = ns / ds;
    }
}

extern "C" void kernel_launch(void* const* d_in, const int* in_sizes, int n_in,
                              void* d_out, int out_size, void* d_ws, size_t ws_size,
                              hipStream_t stream)
{
    const float* X   = (const float*)d_in[0];
    const float* t   = (const float*)d_in[1];
    const float* Mu0 = (const float*)d_in[2];
    const float* Mu1 = (const float*)d_in[3];
    const float* S0  = (const float*)d_in[4];
    const float* S1  = (const float*)d_in[5];
    const float* Lam = (const float*)d_in[6];
    float* out  = (float*)d_out;
    float* part = (float*)d_ws;             // NBLK * PART_STRIDE floats (4.33 MB)

    gmm_fused<<<NBLK, NTHR, 0, stream>>>(X, t, Mu0, Mu1, S0, S1, Lam, part);
    gmm_reduce<<<BB, 256, 0, stream>>>(part, out);
}

// Round 5
// 81.546 us; speedup vs baseline: 1.0120x; 1.0120x over previous
//
#include <hip/hip_runtime.h>
#include <math.h>

// Problem constants
#define BB 128
#define ND 32
#define NIJ 16384
#define EPS2 0.25f
#define EPS4 0.0625f

// Tiling: 512 blocks = 256 ij-chunks x 2 b-halves; 64 ij + 64 b per block.
// 512 thr lane map: nq = bits{0,3}, gij = bits{1,2,4}, bl = bits{5-8}.
// Each thread: 4 b (bl+16*rb) x 8 ij (gij+8*it) x 8 n (nq*8..+8).
// In-loop logw folds over nq use DPP (quad_perm xor1, row_ror:8 == xor8):
// pure VALU, zero LDS-pipe traffic, ~2cyc latency vs ~40cyc ds_swizzle.
#define TIJ 64
#define NBLK 512
#define NTHR 512
#define ROWF 132                // coef row: cA32|cB32|K32|KV32|pad4

// LDS layout (floats)
#define XS_OFF  8448            // X stage [64][36] (this half's rows)
#define CC_OFF  10752
#define LAM_OFF 10816
#define LDS_FL  10880           // 43.5 KB
#define STG_ROW 36

// part layout per slice (packed): num[64][32] @0, den[64] @2048
#define PART_STRIDE 2112
#define DEN_OFF_P 2048

// DPP cross-lane add: v += value from lane (lane ^ mask), mask via ctrl.
// 0xB1 = quad_perm [1,0,3,2] (xor1); 0x4E = quad_perm [2,3,0,1] (xor2);
// 0x128 = row_ror:8 (== xor8 within a 16-lane row).
template <int CTRL>
__device__ __forceinline__ float dpp_xadd(float v)
{
    const int p = __builtin_amdgcn_update_dpp(0, __float_as_int(v),
                                              CTRL, 0xF, 0xF, true);
    return v + __int_as_float(p);
}

__global__ __launch_bounds__(NTHR, 4) void gmm_fused(
    const float* __restrict__ Xg,
    const float* __restrict__ tptr,
    const float* __restrict__ Mu0, const float* __restrict__ Mu1,
    const float* __restrict__ S0,  const float* __restrict__ S1,
    const float* __restrict__ Lam,
    float* __restrict__ part)
{
    __shared__ __align__(16) float lds[LDS_FL];

    const int tid  = threadIdx.x;
    const int blk  = blockIdx.x;
    const int ijc  = blk >> 1;          // ij-chunk 0..255
    const int half = blk & 1;           // b-half
    const int ij0g = ijc * TIJ;
    const int b0   = half * 64;
    const float t   = tptr[0];
    const float omt = 1.0f - t;

    // ---- Phase 1a: this half's X rows -> LDS [64][36], 1 float4/thread ----
    {
        const int idx = tid * 4;           // 2048 floats
        *(float4*)&lds[XS_OFF + (idx >> 5) * STG_ROW + (idx & 31)] =
            *(const float4*)&Xg[b0 * ND + idx];
    }

    // ---- Phase 1b: per-(ij, n) coefficients into LDS ----
    // 64 ij * 32 n = 2048 pairs over 512 threads -> 4 each
#pragma unroll
    for (int k = 0; k < (TIJ * ND) / NTHR; ++k) {
        const int idx = tid + k * NTHR;
        const int ijl = idx >> 5;          // 0..63
        const int n   = idx & 31;
        const int ij  = ij0g + ijl;
        const int i   = ij >> 7;
        const int j   = ij & 127;
        const float s0  = S0[i * ND + n];
        const float s1  = S1[j * ND + n];
        const float mu0 = Mu0[i * ND + n];
        const float mu1 = Mu1[j * ND + n];
        const float Ds  = sqrtf(4.0f * s0 * s1 + EPS4);
        const float Cs  = 0.5f * (Ds - EPS2);
        const float Sigma = omt * omt * s0 + t * t * s1
                          + 2.0f * t * omt * Cs + EPS2 * t * omt;
        const float St  = (t * s1 + omt * Cs) - (omt * s0 + t * Cs) - EPS2 * t;
        const float Mut = omt * mu0 + t * mu1;
        const float v   = mu1 - mu0;
        const float invS = 1.0f / Sigma;
        const float Kf  = St * invS;
        const float cA  = -0.5f * invS;
        const float cB  = Mut * invS;
        lds[ijl * ROWF + n]      = cA;
        lds[ijl * ROWF + 32 + n] = cB;
        lds[ijl * ROWF + 64 + n] = Kf;
        lds[ijl * ROWF + 96 + n] = v - Kf * Mut;
        float cc = cA * Mut * Mut - 0.5f * __logf(Sigma);
        cc = dpp_xadd<0xB1>(cc);           // xor1 (DPP)
        cc = dpp_xadd<0x4E>(cc);           // xor2 (DPP)
        cc += __shfl_xor(cc, 4);
        cc = dpp_xadd<0x128>(cc);          // xor8 (DPP)
        cc += __shfl_xor(cc, 16);
        if (n == 0) lds[CC_OFF + ijl] = cc;
    }
    if (tid < TIJ) lds[LAM_OFF + tid] = Lam[ij0g + tid];

    __syncthreads();

    // ---- Thread mapping: 4 b x 8 ij x 8 n (within this b-half) ----
    // nq on lane bits {0,3} so the logw fold masks are 1 and 8 (DPP-able).
    const int nq  = (tid & 1) | (((tid >> 3) & 1) << 1);
    const int gij = ((tid >> 1) & 3) | (((tid >> 4) & 1) << 2);
    const int bl  = tid >> 5;         // 0..15 -> local b in {bl+16*rb}
    const int n0  = nq * 8;

    // X quarter-rows -> registers
    float x[4][8];
#pragma unroll
    for (int rb = 0; rb < 4; ++rb) {
        const float4 v4 = *(const float4*)&lds[XS_OFF + (bl + 16 * rb) * STG_ROW + n0];
        const float4 w4 = *(const float4*)&lds[XS_OFF + (bl + 16 * rb) * STG_ROW + n0 + 4];
        x[rb][0] = v4.x; x[rb][1] = v4.y; x[rb][2] = v4.z; x[rb][3] = v4.w;
        x[rb][4] = w4.x; x[rb][5] = w4.y; x[rb][6] = w4.z; x[rb][7] = w4.w;
    }

    float num[4][8];
#pragma unroll
    for (int rb = 0; rb < 4; ++rb)
#pragma unroll
        for (int n = 0; n < 8; ++n) num[rb][n] = 0.0f;
    float den[4] = {0.0f, 0.0f, 0.0f, 0.0f};

    // ---- Phase 2: 8 iters; coef quarter-row shared by 4 b ----
    // Wave b128 bank pattern: 16-lane groups hit each bank-word exactly 2x
    // (free 2-way, same as the measured-zero-conflict r4 layout).
#pragma unroll
    for (int it = 0; it < TIJ / 8; ++it) {
        const int ijl = gij + (it << 3);
        const float* __restrict__ row = &lds[ijl * ROWF + n0];
        const float4 a0 = *(const float4*)&row[0];
        const float4 a1 = *(const float4*)&row[4];
        const float4 b0q = *(const float4*)&row[32];
        const float4 b1q = *(const float4*)&row[36];

        float la[4], lb[4];
#pragma unroll
        for (int rb = 0; rb < 4; ++rb) {
            float u = fmaf(fmaf(a0.x, x[rb][0], b0q.x), x[rb][0], 0.0f);
            float v = fmaf(fmaf(a0.y, x[rb][1], b0q.y), x[rb][1], 0.0f);
            u = fmaf(fmaf(a0.z, x[rb][2], b0q.z), x[rb][2], u);
            v = fmaf(fmaf(a0.w, x[rb][3], b0q.w), x[rb][3], v);
            u = fmaf(fmaf(a1.x, x[rb][4], b1q.x), x[rb][4], u);
            v = fmaf(fmaf(a1.y, x[rb][5], b1q.y), x[rb][5], v);
            u = fmaf(fmaf(a1.z, x[rb][6], b1q.z), x[rb][6], u);
            v = fmaf(fmaf(a1.w, x[rb][7], b1q.w), x[rb][7], v);
            la[rb] = u; lb[rb] = v;
        }

        // issue num-coef loads early; latency hidden under fold+exp
        const float4 k0 = *(const float4*)&row[64];
        const float4 k1 = *(const float4*)&row[68];
        const float4 v0 = *(const float4*)&row[96];
        const float4 v1 = *(const float4*)&row[100];
        const float cc0 = lds[CC_OFF + ijl];
        const float lam = lds[LAM_OFF + ijl];

        float w[4];
#pragma unroll
        for (int rb = 0; rb < 4; ++rb) {
            float lw = la[rb] + lb[rb];
            lw = dpp_xadd<0xB1>(lw);       // fold nq bit 0 (lane xor1, DPP)
            lw = dpp_xadd<0x128>(lw);      // fold nq bit 1 (lane xor8, DPP)
            lw = fminf(fmaxf(lw + cc0, -50.0f), 50.0f);
            w[rb] = __expf(lw) * lam;
            den[rb] += w[rb];
        }

#pragma unroll
        for (int rb = 0; rb < 4; ++rb) {
            num[rb][0] = fmaf(w[rb], fmaf(k0.x, x[rb][0], v0.x), num[rb][0]);
            num[rb][1] = fmaf(w[rb], fmaf(k0.y, x[rb][1], v0.y), num[rb][1]);
            num[rb][2] = fmaf(w[rb], fmaf(k0.z, x[rb][2], v0.z), num[rb][2]);
            num[rb][3] = fmaf(w[rb], fmaf(k0.w, x[rb][3], v0.w), num[rb][3]);
            num[rb][4] = fmaf(w[rb], fmaf(k1.x, x[rb][4], v1.x), num[rb][4]);
            num[rb][5] = fmaf(w[rb], fmaf(k1.y, x[rb][5], v1.y), num[rb][5]);
            num[rb][6] = fmaf(w[rb], fmaf(k1.z, x[rb][6], v1.z), num[rb][6]);
            num[rb][7] = fmaf(w[rb], fmaf(k1.w, x[rb][7], v1.w), num[rb][7]);
        }
    }

    // ---- Fold-reduce across the 8 gij groups: 8 cols -> 1 col/lane ----
    // gij value bits {2,1,0} live on lane bits {4,2,1} -> shfl masks {16,4,2}.
#pragma unroll
    for (int rb = 0; rb < 4; ++rb) {
#pragma unroll
        for (int c = 0; c < 4; ++c) {      // gij bit2 (mask 16): 8 -> 4
            const float s = (gij & 4) ? num[rb][c] : num[rb][c + 4];
            const float r = __shfl_xor(s, 16);
            num[rb][c] = ((gij & 4) ? num[rb][c + 4] : num[rb][c]) + r;
        }
#pragma unroll
        for (int c = 0; c < 2; ++c) {      // gij bit1 (mask 4): 4 -> 2
            const float s = (gij & 2) ? num[rb][c] : num[rb][c + 2];
            const float r = __shfl_xor(s, 4);
            num[rb][c] = ((gij & 2) ? num[rb][c + 2] : num[rb][c]) + r;
        }
        {                                   // gij bit0 (mask 2): 2 -> 1
            const float s = (gij & 1) ? num[rb][0] : num[rb][1];
            const float r = __shfl_xor(s, 2);
            num[rb][0] = ((gij & 1) ? num[rb][1] : num[rb][0]) + r;
        }
        den[rb] += __shfl_xor(den[rb], 2);
        den[rb] += __shfl_xor(den[rb], 4);
        den[rb] += __shfl_xor(den[rb], 16);
    }

    // ---- Direct coalesced global store ----
    // Lane holds col nq*8+gij; 32-lane halves cover a full 128-B segment
    // (permuted within -> still coalesced).
    float* __restrict__ dstg = part + (size_t)blk * PART_STRIDE;
    const int col = nq * 8 + gij;
#pragma unroll
    for (int rb = 0; rb < 4; ++rb) {
        dstg[(bl + 16 * rb) * 32 + col] = num[rb][0];
    }
    if (col == 0) {
#pragma unroll
        for (int rb = 0; rb < 4; ++rb) {
            dstg[DEN_OFF_P + bl + 16 * rb] = den[rb];
        }
    }
}

// 128 blocks (one per b), 256 thr = 32 sg x 8 c4. float4 loads:
// per wave-inst 8 slices x 128 B contiguous = 1 KB.
__global__ __launch_bounds__(256) void gmm_reduce(
    const float* __restrict__ part,
    float* __restrict__ out)
{
    const int b    = blockIdx.x;           // 0..127
    const int half = b >> 6;
    const int lb   = b & 63;
    const int tid  = threadIdx.x;
    const int c4   = tid & 7;              // float4 column group
    const int sg   = tid >> 3;             // 0..31 slice-groups

    float4 acc = make_float4(0.0f, 0.0f, 0.0f, 0.0f);
    float accd = 0.0f;
#pragma unroll
    for (int g = 0; g < 8; ++g) {
        const int ijc = sg + g * 32;       // 0..255
        const size_t base = (size_t)(ijc * 2 + half) * PART_STRIDE;
        const float4 v = *(const float4*)&part[base + lb * 32 + c4 * 4];
        acc.x += v.x; acc.y += v.y; acc.z += v.z; acc.w += v.w;
        accd += part[base + DEN_OFF_P + lb];   // broadcast across c4 lanes
    }

    __shared__ float red[32][36];
    *(float4*)&red[sg][c4 * 4] = acc;
    if (c4 == 0) red[sg][32] = accd;
    __syncthreads();

    if (tid < 32) {
        float ns = 0.0f, ds = 0.0f;
#pragma unroll
        for (int k = 0; k < 32; ++k) {
            ns += red[k][tid];
            ds += red[k][32];
        }
        out[b * 32 + tid] = ns / ds;
    }
}

extern "C" void kernel_launch(void* const* d_in, const int* in_sizes, int n_in,
                              void* d_out, int out_size, void* d_ws, size_t ws_size,
                              hipStream_t stream)
{
    const float* X   = (const float*)d_in[0];
    const float* t   = (const float*)d_in[1];
    const float* Mu0 = (const float*)d_in[2];
    const float* Mu1 = (const float*)d_in[3];
    const float* S0  = (const float*)d_in[4];
    const float* S1  = (const float*)d_in[5];
    const float* Lam = (const float*)d_in[6];
    float* out  = (float*)d_out;
    float* part = (float*)d_ws;             // NBLK * PART_STRIDE floats (4.33 MB)

    gmm_fused<<<NBLK, NTHR, 0, stream>>>(X, t, Mu0, Mu1, S0, S1, Lam, part);
    gmm_reduce<<<BB, 256, 0, stream>>>(part, out);
}